// Round 10
// baseline (34.001 us; speedup 1.0000x reference)
//
#include <hip/hip_runtime.h>

#define BATCH       65536
#define FEAT        256
#define NUM_CLASSES 10000
#define ALPHA       0.5f
#define CAP         32     // bucket capacity; Poisson(6.55) max over 10k classes ~21
#define UNROLL      8
#define CBLOCKS     2500
#define CITER       4      // classes per wave (CBLOCKS * CITER = NUM_CLASSES)

// ---------------------------------------------------------------------------
// K1: zero per-class counters + overflow counter
// ---------------------------------------------------------------------------
__global__ __launch_bounds__(256) void zero_kernel(int* __restrict__ count)
{
    int i = blockIdx.x * 256 + threadIdx.x;
    if (i < NUM_CLASSES + 1) count[i] = 0;
}

// ---------------------------------------------------------------------------
// K2: bucket scatter, one sample per thread.
// ---------------------------------------------------------------------------
__global__ __launch_bounds__(256) void bucket_kernel(const int* __restrict__ y_true,
                                                     int* __restrict__ count,
                                                     int* __restrict__ bucket,
                                                     int* __restrict__ ovf)
{
    const int i = blockIdx.x * 256 + threadIdx.x;   // 0 .. BATCH-1
    const int c = y_true[i];
    const int pos = atomicAdd(&count[c], 1);
    if (pos < CAP) {
        bucket[c * CAP + pos] = i;
    } else {
        const int o = atomicAdd(count + NUM_CLASSES, 1);
        ovf[2 * o]     = c;
        ovf[2 * o + 1] = i;
    }
}

// ---------------------------------------------------------------------------
// K3: one wave per class, 4 classes per wave grid-strided, software-pipelined:
// next class's count/bucket/center loads are issued before processing the
// current class (independent -> in flight under the gather). The bucket row
// is loaded UNCONDITIONALLY (full 32 slots, always-mapped) so count[] doesn't
// gate it; garbage slots >= n are masked before any dereference.
// ---------------------------------------------------------------------------
__global__ __launch_bounds__(64) void class_kernel(
    const float* __restrict__ y_pred,
    const float* __restrict__ centers,
    const int*   __restrict__ count,
    const int*   __restrict__ bucket,
    const int*   __restrict__ ovf,
    float*       __restrict__ loss,
    float*       __restrict__ new_centers)
{
    const int lane = threadIdx.x;        // 0..63
    int c = blockIdx.x;

    // prologue prefetch (3 independent loads)
    int    n_nxt  = count[c];
    int    b_nxt  = (lane < CAP) ? bucket[c * CAP + lane] : 0;
    float4 cv_nxt = reinterpret_cast<const float4*>(centers + (size_t)c * FEAT)[lane];

    for (int it = 0; it < CITER; ++it) {
        const int    cc      = c;
        const int    n_total = n_nxt;
        const int    braw    = b_nxt;
        const float4 cv      = cv_nxt;

        c += CBLOCKS;
        if (it + 1 < CITER) {            // issue next class's loads NOW
            n_nxt  = count[c];
            b_nxt  = (lane < CAP) ? bucket[c * CAP + lane] : 0;
            cv_nxt = reinterpret_cast<const float4*>(centers + (size_t)c * FEAT)[lane];
        }

        const int n = min(n_total, CAP);
        float4 s = make_float4(0.f, 0.f, 0.f, 0.f);

        for (int k0 = 0; k0 < n; k0 += UNROLL) {
            int    idx[UNROLL];
            bool   vj [UNROLL];
            float4 y  [UNROLL];
            float  l  [UNROLL];

            #pragma unroll
            for (int j = 0; j < UNROLL; ++j) {
                const int kk = k0 + j;
                vj[j]  = (kk < n);
                idx[j] = __builtin_amdgcn_readlane(braw, vj[j] ? kk : k0);
            }
            #pragma unroll
            for (int j = 0; j < UNROLL; ++j)
                y[j] = reinterpret_cast<const float4*>(y_pred + (size_t)idx[j] * FEAT)[lane];

            #pragma unroll
            for (int j = 0; j < UNROLL; ++j) {
                const float w = vj[j] ? 1.f : 0.f;
                s.x += w * y[j].x;
                s.y += w * y[j].y;
                s.z += w * y[j].z;
                s.w += w * y[j].w;
                const float dx = cv.x - y[j].x, dy = cv.y - y[j].y,
                            dz = cv.z - y[j].z, dw = cv.w - y[j].w;
                l[j] = dx*dx + dy*dy + dz*dz + dw*dw;
            }

            #pragma unroll
            for (int off = 32; off > 0; off >>= 1) {
                #pragma unroll
                for (int j = 0; j < UNROLL; ++j)
                    l[j] += __shfl_down(l[j], off, 64);
            }

            if (lane == 0) {
                #pragma unroll
                for (int j = 0; j < UNROLL; ++j)
                    if (vj[j]) loss[idx[j]] = l[j];
            }
        }

        // overflow fallback (never taken for this data; kept for correctness)
        if (n_total > CAP) {
            const int m = count[NUM_CLASSES];
            for (int o = 0; o < m; ++o) {
                if (ovf[2 * o] == cc) {
                    const int idx = ovf[2 * o + 1];
                    float4 y = reinterpret_cast<const float4*>(y_pred + (size_t)idx * FEAT)[lane];
                    s.x += y.x; s.y += y.y; s.z += y.z; s.w += y.w;
                    float dx = cv.x - y.x, dy = cv.y - y.y,
                          dz = cv.z - y.z, dw = cv.w - y.w;
                    float l = dx*dx + dy*dy + dz*dz + dw*dw;
                    #pragma unroll
                    for (int off = 32; off > 0; off >>= 1)
                        l += __shfl_down(l, off, 64);
                    if (lane == 0) loss[idx] = l;
                }
            }
        }

        const float fn    = (float)n_total;
        const float scale = ALPHA / (fn + 1.0f);
        float4 o;
        o.x = cv.x - (fn * cv.x - s.x) * scale;
        o.y = cv.y - (fn * cv.y - s.y) * scale;
        o.z = cv.z - (fn * cv.z - s.z) * scale;
        o.w = cv.w - (fn * cv.w - s.w) * scale;
        reinterpret_cast<float4*>(new_centers + (size_t)cc * FEAT)[lane] = o;
    }
}

extern "C" void kernel_launch(void* const* d_in, const int* in_sizes, int n_in,
                              void* d_out, int out_size, void* d_ws, size_t ws_size,
                              hipStream_t stream)
{
    const float* y_pred  = (const float*)d_in[0];
    const float* centers = (const float*)d_in[1];
    const int*   y_true  = (const int*)d_in[2];

    float* out         = (float*)d_out;
    float* loss        = out;                 // [BATCH]
    float* new_centers = out + BATCH;         // [NUM_CLASSES * FEAT]

    int* count  = (int*)d_ws;                         // [NUM_CLASSES + 1]
    int* bucket = count + NUM_CLASSES + 1;            // [NUM_CLASSES * CAP]
    int* ovf    = bucket + NUM_CLASSES * CAP;         // [2 * BATCH]

    zero_kernel  <<<(NUM_CLASSES + 256) / 256, 256, 0, stream>>>(count);
    bucket_kernel<<<BATCH / 256, 256, 0, stream>>>(y_true, count, bucket, ovf);
    class_kernel <<<CBLOCKS, 64, 0, stream>>>(
        y_pred, centers, count, bucket, ovf, loss, new_centers);
}

// Round 11
// 32.555 us; speedup vs baseline: 1.0444x; 1.0444x over previous
//
#include <hip/hip_runtime.h>

#define BATCH       65536
#define FEAT        256
#define NUM_CLASSES 10000
#define ALPHA       0.5f
#define CAP         32     // bucket capacity; Poisson(6.55) max over 10k classes ~21
#define UNROLL      8

// ---------------------------------------------------------------------------
// K1: zero per-class counters + overflow counter
// ---------------------------------------------------------------------------
__global__ __launch_bounds__(256) void zero_kernel(int* __restrict__ count)
{
    int i = blockIdx.x * 256 + threadIdx.x;
    if (i < NUM_CLASSES + 1) count[i] = 0;
}

// ---------------------------------------------------------------------------
// K2: bucket scatter, one sample per thread.
// ---------------------------------------------------------------------------
__global__ __launch_bounds__(256) void bucket_kernel(const int* __restrict__ y_true,
                                                     int* __restrict__ count,
                                                     int* __restrict__ bucket,
                                                     int* __restrict__ ovf)
{
    const int i = blockIdx.x * 256 + threadIdx.x;   // 0 .. BATCH-1
    const int c = y_true[i];
    const int pos = atomicAdd(&count[c], 1);
    if (pos < CAP) {
        bucket[c * CAP + pos] = i;
    } else {
        const int o = atomicAdd(count + NUM_CLASSES, 1);
        ovf[2 * o]     = c;
        ovf[2 * o + 1] = i;
    }
}

// ---------------------------------------------------------------------------
// K3: 4 waves/block (max TLP config, round 8) + x8 gather unroll (round 9)
// + 2-epoch load structure: count, bucket row, and center row are issued as
// THREE INDEPENDENT loads (bucket row loaded unconditionally, garbage slots
// masked after the fact) so the only dependent epoch is bucket -> row gather.
// ---------------------------------------------------------------------------
__global__ __launch_bounds__(256) void class_kernel(
    const float* __restrict__ y_pred,
    const float* __restrict__ centers,
    const int*   __restrict__ count,
    const int*   __restrict__ bucket,
    const int*   __restrict__ ovf,
    float*       __restrict__ loss,
    float*       __restrict__ new_centers)
{
    const int wave = threadIdx.x >> 6;
    const int lane = threadIdx.x & 63;
    const int c    = blockIdx.x * 4 + wave;      // exact: 2500*4 = 10000
    if (c >= NUM_CLASSES) return;

    // epoch 1: three independent loads, all in flight together
    const int    n_total = count[c];
    const int    braw    = bucket[c * CAP + (lane & 31)];   // unconditional 128B row
    const float4 cv      = reinterpret_cast<const float4*>(centers + (size_t)c * FEAT)[lane];

    const int n = min(n_total, CAP);
    float4 s = make_float4(0.f, 0.f, 0.f, 0.f);

    for (int k0 = 0; k0 < n; k0 += UNROLL) {
        int    idx[UNROLL];
        bool   vj [UNROLL];
        float4 y  [UNROLL];
        float  l  [UNROLL];

        #pragma unroll
        for (int j = 0; j < UNROLL; ++j) {
            const int kk = k0 + j;
            vj[j]  = (kk < n);
            idx[j] = __builtin_amdgcn_readlane(braw, vj[j] ? kk : k0);  // slot k in lane k (k<32)
        }
        // epoch 2: up to 8 independent 1KB row gathers in flight
        #pragma unroll
        for (int j = 0; j < UNROLL; ++j)
            y[j] = reinterpret_cast<const float4*>(y_pred + (size_t)idx[j] * FEAT)[lane];

        #pragma unroll
        for (int j = 0; j < UNROLL; ++j) {
            const float w = vj[j] ? 1.f : 0.f;
            s.x += w * y[j].x;
            s.y += w * y[j].y;
            s.z += w * y[j].z;
            s.w += w * y[j].w;
            const float dx = cv.x - y[j].x, dy = cv.y - y[j].y,
                        dz = cv.z - y[j].z, dw = cv.w - y[j].w;
            l[j] = dx*dx + dy*dy + dz*dz + dw*dw;
        }

        // 8 interleaved butterfly reduces (independent cross-lane chains)
        #pragma unroll
        for (int off = 32; off > 0; off >>= 1) {
            #pragma unroll
            for (int j = 0; j < UNROLL; ++j)
                l[j] += __shfl_down(l[j], off, 64);
        }

        if (lane == 0) {
            #pragma unroll
            for (int j = 0; j < UNROLL; ++j)
                if (vj[j]) loss[idx[j]] = l[j];
        }
    }

    // overflow fallback (never taken for this data; kept for correctness)
    if (n_total > CAP) {
        const int m = count[NUM_CLASSES];
        for (int o = 0; o < m; ++o) {
            if (ovf[2 * o] == c) {
                const int idx = ovf[2 * o + 1];
                float4 y = reinterpret_cast<const float4*>(y_pred + (size_t)idx * FEAT)[lane];
                s.x += y.x; s.y += y.y; s.z += y.z; s.w += y.w;
                float dx = cv.x - y.x, dy = cv.y - y.y,
                      dz = cv.z - y.z, dw = cv.w - y.w;
                float l = dx*dx + dy*dy + dz*dz + dw*dw;
                #pragma unroll
                for (int off = 32; off > 0; off >>= 1)
                    l += __shfl_down(l, off, 64);
                if (lane == 0) loss[idx] = l;
            }
        }
    }

    const float fn    = (float)n_total;
    const float scale = ALPHA / (fn + 1.0f);
    float4 o;
    o.x = cv.x - (fn * cv.x - s.x) * scale;
    o.y = cv.y - (fn * cv.y - s.y) * scale;
    o.z = cv.z - (fn * cv.z - s.z) * scale;
    o.w = cv.w - (fn * cv.w - s.w) * scale;
    reinterpret_cast<float4*>(new_centers + (size_t)c * FEAT)[lane] = o;
}

extern "C" void kernel_launch(void* const* d_in, const int* in_sizes, int n_in,
                              void* d_out, int out_size, void* d_ws, size_t ws_size,
                              hipStream_t stream)
{
    const float* y_pred  = (const float*)d_in[0];
    const float* centers = (const float*)d_in[1];
    const int*   y_true  = (const int*)d_in[2];

    float* out         = (float*)d_out;
    float* loss        = out;                 // [BATCH]
    float* new_centers = out + BATCH;         // [NUM_CLASSES * FEAT]

    int* count  = (int*)d_ws;                         // [NUM_CLASSES + 1]
    int* bucket = count + NUM_CLASSES + 1;            // [NUM_CLASSES * CAP]
    int* ovf    = bucket + NUM_CLASSES * CAP;         // [2 * BATCH]

    zero_kernel  <<<(NUM_CLASSES + 256) / 256, 256, 0, stream>>>(count);
    bucket_kernel<<<BATCH / 256, 256, 0, stream>>>(y_true, count, bucket, ovf);
    class_kernel <<<NUM_CLASSES / 4, 256, 0, stream>>>(
        y_pred, centers, count, bucket, ovf, loss, new_centers);
}